// Round 22
// baseline (132.911 us; speedup 1.0000x reference)
//
#include <hip/hip_runtime.h>
#include <hip/hip_bf16.h>
#include <math.h>

#define GLOBAL_AS __attribute__((address_space(1)))
#define LDS_AS __attribute__((address_space(3)))

typedef int i32x4 __attribute__((ext_vector_type(4)));

#define N 8192
#define D 1024
#define QSCALE 18.0f
#define INV_S2 (1.0f / (QSCALE * QSCALE))
// 3-adic histogram layout: H_k (size 3^k) at OFF_k = (3^k-3)/2, k=1..10.
#define HOFF1 0
#define HOFF2 3
#define HOFF3 12
#define HOFF4 39
#define HOFF5 120
#define HOFF6 363
#define HOFF7 1092
#define HOFF8 3279
#define HOFF9 9840
#define HOFF10 29523
#define HTOT 88572

#if __has_builtin(__builtin_amdgcn_sqrtf)
#define FSQRT(x) __builtin_amdgcn_sqrtf(x)  // raw v_sqrt_f32, ~1ulp
#else
#define FSQRT(x) sqrtf(x)
#endif

// Convert z (fp32) -> int8 (q = clamp(rint(x*18), +-127)), exact fp32 row
// sums of squares; piggyback zeroing of hist AND Pws (gram's transposed
// writes now touch only even slots -> odd slots must read as 0 in r1).
__global__ __launch_bounds__(256) void prep_kernel(
    const float* __restrict__ z, signed char* __restrict__ zq,
    float* __restrict__ sq, int* __restrict__ hist, float* __restrict__ Pws) {
  const int r = blockIdx.x, t = threadIdx.x;
  if (r < 346) {  // zero 88572 ints for hist_kernel (runs after, stream order)
    const int o = r * 256 + t;
    if (o < HTOT) hist[o] = 0;
  }
  if (r < 4096) Pws[(size_t)r * 256 + t] = 0.f;  // 128*N floats
  const float4 v = *(const float4*)(z + (size_t)r * D + t * 4);
  float f[4] = {v.x, v.y, v.z, v.w};
  int qq[4];
  float s = 0.f;
#pragma unroll
  for (int u = 0; u < 4; ++u) {
    float x = f[u];
    s = fmaf(x, x, s);
    int q = (int)rintf(x * QSCALE);
    q = max(-127, min(127, q));
    qq[u] = q;
  }
  const unsigned packed = (unsigned)(qq[0] & 255) | ((unsigned)(qq[1] & 255) << 8) |
                          ((unsigned)(qq[2] & 255) << 16) | ((unsigned)(qq[3] & 255) << 24);
  *(unsigned*)(zq + (size_t)r * D + t * 4) = packed;
  // deterministic block reduction
#pragma unroll
  for (int o = 32; o >= 1; o >>= 1) s += __shfl_down(s, o, 64);
  __shared__ float red[4];
  const int lane = t & 63, wv = t >> 6;
  if (lane == 0) red[wv] = s;
  __syncthreads();
  if (t == 0) sq[r] = ((red[0] + red[1]) + red[2]) + red[3];
}

// Histogram build: atomics into H_8 and H_10 only (spread counters, low
// contention; integer atomics = deterministic). idx < 3^10.
__global__ __launch_bounds__(256) void hist_kernel(
    const int* __restrict__ idx, int* __restrict__ hist) {
  const unsigned mi = (unsigned)idx[blockIdx.x * 256 + threadIdx.x];
  atomicAdd(&hist[HOFF8 + (mi % 6561u)], 1);
  atomicAdd(&hist[HOFF10 + mi], 1);
}

// Fold: blocks 0..76 derive H_9 from H_10; block 77 derives H_7..H_1 from
// H_8 in LDS (3279 ints, sequential levels with barriers).
__global__ __launch_bounds__(256) void fold_kernel(int* __restrict__ hist) {
  const int b = blockIdx.x, t = threadIdx.x;
  if (b < 77) {
    const int r = b * 256 + t;
    if (r < 19683)
      hist[HOFF9 + r] =
          hist[HOFF10 + r] + hist[HOFF10 + r + 19683] + hist[HOFF10 + r + 39366];
    return;
  }
  // b == 77: levels 7..1. LDS: l7@0(2187) l6@2187(729) l5@2916(243)
  // l4@3159(81) l3@3240(27) l2@3267(9) l1@3276(3).
  __shared__ int lh[3279];
  for (int r = t; r < 2187; r += 256)
    lh[r] = hist[HOFF8 + r] + hist[HOFF8 + r + 2187] + hist[HOFF8 + r + 4374];
  __syncthreads();
  for (int r = t; r < 729; r += 256) lh[2187 + r] = lh[r] + lh[r + 729] + lh[r + 1458];
  __syncthreads();
  for (int r = t; r < 243; r += 256)
    lh[2916 + r] = lh[2187 + r] + lh[2187 + r + 243] + lh[2187 + r + 486];
  __syncthreads();
  for (int r = t; r < 81; r += 256)
    lh[3159 + r] = lh[2916 + r] + lh[2916 + r + 81] + lh[2916 + r + 162];
  __syncthreads();
  for (int r = t; r < 27; r += 256)
    lh[3240 + r] = lh[3159 + r] + lh[3159 + r + 27] + lh[3159 + r + 54];
  __syncthreads();
  if (t < 9) lh[3267 + t] = lh[3240 + t] + lh[3240 + t + 9] + lh[3240 + t + 18];
  __syncthreads();
  if (t < 3) lh[3276 + t] = lh[3267 + t] + lh[3267 + t + 3] + lh[3267 + t + 6];
  __syncthreads();
  for (int r = t; r < 2187; r += 256) hist[HOFF7 + r] = lh[r];
  for (int r = t; r < 729; r += 256) hist[HOFF6 + r] = lh[2187 + r];
  for (int r = t; r < 243; r += 256) hist[HOFF5 + r] = lh[2916 + r];
  if (t < 81) hist[HOFF4 + t] = lh[3159 + t];
  if (t < 27) hist[HOFF3 + t] = lh[3240 + t];
  if (t < 9) hist[HOFF2 + t] = lh[3267 + t];
  if (t < 3) hist[HOFF1 + t] = lh[3276 + t];
}

// Lower-triangle 128x128 tile gram over K=1024 int8, BK=128 single-buffer,
// TWO-WAVE blocks (128 thr): each wave owns a 128x64 column-half.
// Rationale (r21 accounting: LDS port ~27us = largest resource):
//  - bytes/MFMA 512 -> 384 (per kc: 8 A + 4 B frag loads feed 32 MFMA);
//    block LDS-read traffic 512KB -> 384KB.
//  - per-wave MFMA per barrier-pair doubles (256 -> 512).
//  - acc[8][4]=128 AGPR + ~70 arch fits the 256-reg cap of
//    launch_bounds(128,2); 4 blocks/CU expected (LDS 4x33KB).
// Epilogue: r21's 243-float-LUT form; m runs 0..7; transposed column sums
// are complete per tile -> single slot ib*2 (odd slots stay zero; Pws
// pre-zeroed in prep).
__global__ __launch_bounds__(128, 2) void gram_kernel(
    const signed char* __restrict__ zq,
    const float* __restrict__ sq, const int* __restrict__ idx,
    float* __restrict__ Pws) {
  __shared__ __align__(16) signed char lds[2 * 128 * 128];  // A, B (32 KiB)
  __shared__ float w243f[244];  // w by diff%243
  __shared__ float lut12f[12];  // w by v3 value; [11] = diff==0
  // triangle decode: blockIdx.x = ib*(ib+1)/2 + jb, jb <= ib
  const int t = blockIdx.x;
  int ibv = (int)((sqrtf(8.f * (float)t + 1.f) - 1.f) * 0.5f);
  while ((ibv + 1) * (ibv + 2) / 2 <= t) ++ibv;
  while (ibv * (ibv + 1) / 2 > t) --ibv;
  const int ib = __builtin_amdgcn_readfirstlane(ibv);
  const int jb = __builtin_amdgcn_readfirstlane(t - ibv * (ibv + 1) / 2);

  const int tid = threadIdx.x;
  const int lane = tid & 63;
  const int wc = tid >> 6;  // wave = column half
  const int r0 = lane & 15, kg = lane >> 4;

  if (tid < 12) {
    const float Pl = (tid == 11) ? 0.f : -2.f * exp2f(-1.5849625007211562f * (float)tid);
    lut12f[tid] = exp2f(1.4426950408889634f * Pl);
  }
  for (int o = tid; o < 243; o += 128) {
    int rr = o, v = 0;
    if (rr > 0) {
      while (rr % 3 == 0) { rr /= 3; ++v; }
    }
    w243f[o] = exp2f(1.4426950408889634f * (-2.f * exp2f(-1.5849625007211562f * (float)v)));
  }

  // --- staging addressing (128 threads) ---
  // inst i8 covers rows i8*16+(t>>4), unit col cs = t&7 for... rows via
  // t>>3 (16 rows/inst-group), cs = t&7; source col unit = cs ^ (row&7).
  const unsigned vbase =
      ((unsigned)(tid >> 3) * 1024u) + ((unsigned)((tid & 7) ^ ((tid >> 3) & 7)) * 16u);
  const char* aBase = (const char*)(zq + (size_t)ib * 128 * D) + vbase;
  const char* bBase = (const char*)(zq + (size_t)jb * 128 * D) + vbase;
  char* ldsc = (char*)&lds[0];

  // --- LDS read addressing (kc=1 = base ^ 64) ---
  const int ub = kg ^ (r0 & 3);
  const int kcx = (r0 >> 2) & 1;
  const unsigned aoff0 = (unsigned)(r0 * 128 + (kcx * 4 + ub) * 16);  // + m*2048
  const unsigned boff0 =
      (unsigned)(16384 + (wc * 64 + r0) * 128 + (kcx * 4 + ub) * 16);  // + n*2048

  i32x4 acc[8][4];
  const i32x4 vz = {0, 0, 0, 0};
#pragma unroll
  for (int m = 0; m < 8; ++m)
#pragma unroll
    for (int n = 0; n < 4; ++n) acc[m][n] = vz;

  // K = 1024: 8 steps of BK=128 (128B per row-step)
#pragma unroll 1
  for (int ks = 0; ks < 8; ++ks) {
    const char* aP = aBase + (unsigned)(ks * 128);
    char* ldA = ldsc + tid * 16;
    __syncthreads();
#pragma unroll 1
    for (int i8 = 0; i8 < 8; ++i8) {
      __builtin_amdgcn_global_load_lds((const GLOBAL_AS void*)aP,
                                       (LDS_AS void*)ldA, 16, 0, 0);
      aP += 16384; ldA += 2048;  // 16 rows x 1024B global; 16 x 128B LDS
    }
    const char* bP = bBase + (unsigned)(ks * 128);
    char* ldB = ldsc + 16384 + tid * 16;
#pragma unroll 1
    for (int i8 = 0; i8 < 8; ++i8) {
      __builtin_amdgcn_global_load_lds((const GLOBAL_AS void*)bP,
                                       (LDS_AS void*)ldB, 16, 0, 0);
      bP += 16384; ldB += 2048;
    }
    __syncthreads();

#pragma unroll
    for (int kc = 0; kc < 2; ++kc) {
      const unsigned ax = aoff0 ^ (unsigned)(kc * 64);
      const unsigned bx = boff0 ^ (unsigned)(kc * 64);
      i32x4 b[4];
#pragma unroll
      for (int n = 0; n < 4; ++n) b[n] = *(const i32x4*)(ldsc + bx + n * 2048);
#pragma unroll
      for (int m = 0; m < 8; ++m) {
        const i32x4 a = *(const i32x4*)(ldsc + ax + m * 2048);
#pragma unroll
        for (int n = 0; n < 4; ++n)
          acc[m][n] = __builtin_amdgcn_mfma_i32_16x16x64_i8(a, b[n], acc[m][n], 0, 0, 0);
      }
    }
  }

  // ---- Epilogue: ws = SUM_j w * sqrt(max(sq_i+sq_j-2g,0)) ----
  const int ibase = ib * 128 + kg * 4;
  const int jbase = jb * 128 + wc * 64 + r0;
  float sqj[4];
  int idxj[4];
#pragma unroll
  for (int n = 0; n < 4; ++n) {
    sqj[n] = sq[jbase + n * 16];
    idxj[n] = idx[jbase + n * 16];
  }
  const int dslot = jb * 2 + wc;
  float cws[4] = {0.f, 0.f, 0.f, 0.f};  // column (transposed) accumulators
#pragma unroll
  for (int m = 0; m < 8; ++m) {
#pragma unroll
    for (int q = 0; q < 4; ++q) {
      const int i = ibase + m * 16 + q;
      const float sqi = sq[i];
      const int idxi = idx[i];
      float ws = 0.f;
#pragma unroll
      for (int n = 0; n < 4; ++n) {
        const int j = jbase + n * 16;
        const float g = (float)acc[m][n][q] * INV_S2;
        const float d2 = sqi + sqj[n] - 2.f * g;
        const float dd = FSQRT(fmaxf(d2, 0.f));
        const int di = idxi - idxj[n];
        const unsigned diff = (unsigned)(di < 0 ? -di : di);
        // w via 243-entry LDS table (r19-measured faster than branchless)
        const unsigned qd = __umulhi(diff, 17674763u);
        const unsigned rm = diff - qd * 243u;
        float w = w243f[rm];
        if (__builtin_expect(rm == 0u, 0)) {
          int vvv;
          if (diff == 0u) {
            vvv = 11;
          } else {  // v = 5 + v3(qd), qd in 1..242
            unsigned q2 = qd, t2;
            vvv = 5;
            t2 = q2 * 1749801491u; if (t2 <= 159072862u)  { q2 = t2; vvv += 3; }
            t2 = q2 * 2863311531u; if (t2 <= 1431655765u) { q2 = t2; vvv += 1; }
            t2 = q2 * 2863311531u; if (t2 <= 1431655765u) { vvv += 1; }
          }
          w = lut12f[vvv];
        }
        const float wdd = (i == j) ? 0.f : w * dd;
        ws += wdd;
        cws[n] += wdd;
      }
      // row reduce across the 16 lanes holding this C-row (lane bits 0..3)
#pragma unroll
      for (int o = 1; o < 16; o <<= 1) ws += __shfl_xor(ws, o, 64);
      if (r0 == 0) Pws[(size_t)dslot * N + i] = ws;
    }
  }
  // transposed (column) partials: complete per tile (wave spans all 128 i)
  // -> rows of block jb, slot ib*2 (odd slots stay zero from prep).
  if (ib != jb) {
    const int tslot = ib * 2;
#pragma unroll
    for (int nn = 0; nn < 4; ++nn) {
      float a = cws[nn];
#pragma unroll
      for (int o = 16; o < 64; o <<= 1) a += __shfl_xor(a, o, 64);
      if (kg == 0) Pws[(size_t)tslot * N + jbase + nn * 16] = a;
    }
  }
}

// Per-row: Z_i/PL_i from 3-adic histograms (exact: v3>=k <=> equal mod 3^k),
// then T_i = (PL_i + 2*SUM ws)/Z_i - log Z_i.
__global__ __launch_bounds__(256) void r1_kernel(
    const float* __restrict__ Pws, const int* __restrict__ hist,
    const int* __restrict__ idx, float* __restrict__ t) {
  const int row = blockIdx.x * 256 + threadIdx.x;
  float ws = 0.f;
  for (int s = 0; s < 128; ++s) ws += Pws[(size_t)s * N + row];
  const unsigned mi = (unsigned)idx[row];
  int H[11];
  H[0] = N;
  H[1] = hist[HOFF1 + (mi % 3u)];
  H[2] = hist[HOFF2 + (mi % 9u)];
  H[3] = hist[HOFF3 + (mi % 27u)];
  H[4] = hist[HOFF4 + (mi % 81u)];
  H[5] = hist[HOFF5 + (mi % 243u)];
  H[6] = hist[HOFF6 + (mi % 729u)];
  H[7] = hist[HOFF7 + (mi % 2187u)];
  H[8] = hist[HOFF8 + (mi % 6561u)];
  H[9] = hist[HOFF9 + (mi % 19683u)];
  H[10] = hist[HOFF10 + mi];
  float Z = 0.f, PL = 0.f;
#pragma unroll
  for (int k = 0; k < 10; ++k) {
    const float pl = -2.f * exp2f(-1.5849625007211562f * (float)k);
    const float w = exp2f(1.4426950408889634f * pl);
    const float cnt = (float)(H[k] - H[k + 1]);
    Z = fmaf(cnt, w, Z);
    PL = fmaf(cnt, w * pl, PL);
  }
  Z += (float)H[10];  // diff==0 class: w=1, Pl=0
  t[row] = (PL + 2.f * ws) / Z - logf(Z);
}

// Final deterministic scalar reduction.
__global__ __launch_bounds__(256) void r2_kernel(const float* __restrict__ t,
                                                 float* __restrict__ out) {
  __shared__ float red[256];
  float s = 0.f;
  for (int r = threadIdx.x; r < N; r += 256) s += t[r];
  red[threadIdx.x] = s;
  __syncthreads();
  for (int o = 128; o > 0; o >>= 1) {
    if (threadIdx.x < (unsigned)o) red[threadIdx.x] += red[threadIdx.x + o];
    __syncthreads();
  }
  if (threadIdx.x == 0) out[0] = red[0] / (float)N;
}

extern "C" void kernel_launch(void* const* d_in, const int* in_sizes, int n_in,
                              void* d_out, int out_size, void* d_ws, size_t ws_size,
                              hipStream_t stream) {
  const float* z = (const float*)d_in[0];
  const int* idx = (const int*)d_in[1];
  float* out = (float*)d_out;
  char* ws = (char*)d_ws;
  // workspace layout (~13 MB used)
  signed char* zq = (signed char*)ws;                                  // 8 MB
  float* sq = (float*)(ws + ((size_t)32 << 20));                       // 32 KB
  float* Pws = (float*)(ws + ((size_t)32 << 20) + ((size_t)64 << 10)); // 4 MB
  int* hist = (int*)(Pws + (size_t)128 * N);                           // 354 KB
  float* tt = (float*)(hist + HTOT);                                   // 32 KB

  prep_kernel<<<N, 256, 0, stream>>>(z, zq, sq, hist, Pws);
  hist_kernel<<<32, 256, 0, stream>>>(idx, hist);
  fold_kernel<<<78, 256, 0, stream>>>(hist);
  gram_kernel<<<64 * 65 / 2, 128, 0, stream>>>(zq, sq, idx, Pws);
  r1_kernel<<<32, 256, 0, stream>>>(Pws, hist, idx, tt);
  r2_kernel<<<1, 256, 0, stream>>>(tt, out);
}

// Round 23
// 105.662 us; speedup vs baseline: 1.2579x; 1.2579x over previous
//
#include <hip/hip_runtime.h>
#include <hip/hip_bf16.h>
#include <math.h>

#define GLOBAL_AS __attribute__((address_space(1)))
#define LDS_AS __attribute__((address_space(3)))

typedef int i32x4 __attribute__((ext_vector_type(4)));

#define N 8192
#define D 1024
#define QSCALE 18.0f
#define INV_S2 (1.0f / (QSCALE * QSCALE))
// 3-adic histogram layout: H_k (size 3^k) at OFF_k = (3^k-3)/2, k=1..10.
#define HOFF1 0
#define HOFF2 3
#define HOFF3 12
#define HOFF4 39
#define HOFF5 120
#define HOFF6 363
#define HOFF7 1092
#define HOFF8 3279
#define HOFF9 9840
#define HOFF10 29523
#define HTOT 88572

#if __has_builtin(__builtin_amdgcn_sqrtf)
#define FSQRT(x) __builtin_amdgcn_sqrtf(x)  // raw v_sqrt_f32, ~1ulp
#else
#define FSQRT(x) sqrtf(x)
#endif

// Convert z (fp32) -> int8 (q = clamp(rint(x*18), +-127)), exact fp32 row
// sums of squares, and (piggybacked) zero the histogram buffer.
__global__ __launch_bounds__(256) void prep_kernel(
    const float* __restrict__ z, signed char* __restrict__ zq,
    float* __restrict__ sq, int* __restrict__ hist) {
  const int r = blockIdx.x, t = threadIdx.x;
  if (r < 346) {  // zero 88572 ints for hist_kernel (runs after, stream order)
    const int o = r * 256 + t;
    if (o < HTOT) hist[o] = 0;
  }
  const float4 v = *(const float4*)(z + (size_t)r * D + t * 4);
  float f[4] = {v.x, v.y, v.z, v.w};
  int qq[4];
  float s = 0.f;
#pragma unroll
  for (int u = 0; u < 4; ++u) {
    float x = f[u];
    s = fmaf(x, x, s);
    int q = (int)rintf(x * QSCALE);
    q = max(-127, min(127, q));
    qq[u] = q;
  }
  const unsigned packed = (unsigned)(qq[0] & 255) | ((unsigned)(qq[1] & 255) << 8) |
                          ((unsigned)(qq[2] & 255) << 16) | ((unsigned)(qq[3] & 255) << 24);
  *(unsigned*)(zq + (size_t)r * D + t * 4) = packed;
  // deterministic block reduction
#pragma unroll
  for (int o = 32; o >= 1; o >>= 1) s += __shfl_down(s, o, 64);
  __shared__ float red[4];
  const int lane = t & 63, wv = t >> 6;
  if (lane == 0) red[wv] = s;
  __syncthreads();
  if (t == 0) sq[r] = ((red[0] + red[1]) + red[2]) + red[3];
}

// Histogram build: atomics into H_8 and H_10 only (spread counters, low
// contention; integer atomics = deterministic). idx < 3^10.
__global__ __launch_bounds__(256) void hist_kernel(
    const int* __restrict__ idx, int* __restrict__ hist) {
  const unsigned mi = (unsigned)idx[blockIdx.x * 256 + threadIdx.x];
  atomicAdd(&hist[HOFF8 + (mi % 6561u)], 1);
  atomicAdd(&hist[HOFF10 + mi], 1);
}

// Fold: blocks 0..76 derive H_9 from H_10; block 77 derives H_7..H_1 from
// H_8 in LDS (3279 ints, sequential levels with barriers).
__global__ __launch_bounds__(256) void fold_kernel(int* __restrict__ hist) {
  const int b = blockIdx.x, t = threadIdx.x;
  if (b < 77) {
    const int r = b * 256 + t;
    if (r < 19683)
      hist[HOFF9 + r] =
          hist[HOFF10 + r] + hist[HOFF10 + r + 19683] + hist[HOFF10 + r + 39366];
    return;
  }
  // b == 77: levels 7..1. LDS: l7@0(2187) l6@2187(729) l5@2916(243)
  // l4@3159(81) l3@3240(27) l2@3267(9) l1@3276(3).
  __shared__ int lh[3279];
  for (int r = t; r < 2187; r += 256)
    lh[r] = hist[HOFF8 + r] + hist[HOFF8 + r + 2187] + hist[HOFF8 + r + 4374];
  __syncthreads();
  for (int r = t; r < 729; r += 256) lh[2187 + r] = lh[r] + lh[r + 729] + lh[r + 1458];
  __syncthreads();
  for (int r = t; r < 243; r += 256)
    lh[2916 + r] = lh[2187 + r] + lh[2187 + r + 243] + lh[2187 + r + 486];
  __syncthreads();
  for (int r = t; r < 81; r += 256)
    lh[3159 + r] = lh[2916 + r] + lh[2916 + r + 81] + lh[2916 + r + 162];
  __syncthreads();
  for (int r = t; r < 27; r += 256)
    lh[3240 + r] = lh[3159 + r] + lh[3159 + r + 27] + lh[3159 + r + 54];
  __syncthreads();
  if (t < 9) lh[3267 + t] = lh[3240 + t] + lh[3240 + t + 9] + lh[3240 + t + 18];
  __syncthreads();
  if (t < 3) lh[3276 + t] = lh[3267 + t] + lh[3267 + t + 3] + lh[3267 + t + 6];
  __syncthreads();
  for (int r = t; r < 2187; r += 256) hist[HOFF7 + r] = lh[r];
  for (int r = t; r < 729; r += 256) hist[HOFF6 + r] = lh[2187 + r];
  for (int r = t; r < 243; r += 256) hist[HOFF5 + r] = lh[2916 + r];
  if (t < 81) hist[HOFF4 + t] = lh[3159 + t];
  if (t < 27) hist[HOFF3 + t] = lh[3240 + t];
  if (t < 9) hist[HOFF2 + t] = lh[3267 + t];
  if (t < 3) hist[HOFF1 + t] = lh[3276 + t];
}

// Lower-triangle 128x128 tile gram over K=1024 int8, BK=64 DOUBLE-BUFFERED
// with counted vmcnt, at ISO-OCCUPANCY with r21 (LDS 2x16KB = 32KB, same
// 33.8KB block footprint, (256,3) -> 3 blocks/CU).
// Rationale: r7/r20's dbuf failures were confounded by occupancy loss
// (dbuf's 2x LDS cost a resident block); r22's 2-wave failure was a TLP
// loss. This is the clean iso-occupancy test of counted-vmcnt pipelining:
//   STAGE(ks+1 -> other buf)  ; 4 global_load_lds issued early
//   vmcnt(4)                  ; own current-step loads landed, next's fly
//   s_barrier ; 8 ds_read + 16 MFMA ; s_barrier  ; seal before restage
// Swizzle for 4-unit (64B) rows, both-sides: swz(row)=(row&3)^((row>>2)&3);
// per-16-lane bank check: uniform 2-way = free (m136).
// Epilogue = r21 verbatim (4-wave quadrants, 243-float-LUT weights).
__global__ __launch_bounds__(256, 3) void gram_kernel(
    const signed char* __restrict__ zq,
    const float* __restrict__ sq, const int* __restrict__ idx,
    float* __restrict__ Pws) {
  __shared__ __align__(16) signed char lds[2 * 2 * 64 * 128];  // dbuf x (A,B) = 32 KiB
  __shared__ float w243f[244];  // w by diff%243
  __shared__ float lut12f[12];  // w by v3 value; [11] = diff==0
  // triangle decode: blockIdx.x = ib*(ib+1)/2 + jb, jb <= ib
  const int t = blockIdx.x;
  int ibv = (int)((sqrtf(8.f * (float)t + 1.f) - 1.f) * 0.5f);
  while ((ibv + 1) * (ibv + 2) / 2 <= t) ++ibv;
  while (ibv * (ibv + 1) / 2 > t) --ibv;
  const int ib = __builtin_amdgcn_readfirstlane(ibv);
  const int jb = __builtin_amdgcn_readfirstlane(t - ibv * (ibv + 1) / 2);

  const int tid = threadIdx.x;
  const int lane = tid & 63, wv = tid >> 6;
  const int wr = wv >> 1, wc = wv & 1;
  const int r0 = lane & 15, kg = lane >> 4;

  if (tid < 12) {
    const float Pl = (tid == 11) ? 0.f : -2.f * exp2f(-1.5849625007211562f * (float)tid);
    lut12f[tid] = exp2f(1.4426950408889634f * Pl);
  }
  if (tid < 243) {
    int rr = tid, v = 0;
    if (rr > 0) {
      while (rr % 3 == 0) { rr /= 3; ++v; }
    }
    w243f[tid] = exp2f(1.4426950408889634f * (-2.f * exp2f(-1.5849625007211562f * (float)v)));
  }

  // --- staging addressing ---
  // Thread t covers row (t>>2) (of each 64-row inst-group), unit cs = t&3.
  // Source col unit = cs ^ (row&3) ^ ((row>>2)&3); LDS dest linear tid*16.
  // (row>>2)&3 == (tid>>4)&3 for both inst-groups (64 = 0 mod 16 rows).
  const unsigned vstage =
      ((unsigned)(tid >> 2) * 1024u) +
      ((unsigned)((tid & 3) ^ ((tid >> 2) & 3) ^ ((tid >> 4) & 3)) * 16u);
  const char* aBase = (const char*)(zq + (size_t)ib * 128 * D) + vstage;
  const char* bBase = (const char*)(zq + (size_t)jb * 128 * D) + vstage;
  char* ldsc = (char*)&lds[0];

  // --- LDS read addressing: global unit kg of row r -> LDS unit
  // kg ^ (r0&3) ^ ((r0>>2)&3) (uniform over m/wr: their row offsets are
  // multiples of 16). byte = row*64 + u*16; frag m at +m*1024.
  const unsigned u0 = (unsigned)((kg ^ (r0 & 3) ^ ((r0 >> 2) & 3)) & 3);
  const unsigned aoff0 = (unsigned)((wr * 64 + r0) * 64) + u0 * 16u;
  const unsigned boff0 = 8192u + (unsigned)((wc * 64 + r0) * 64) + u0 * 16u;

  i32x4 acc[4][4];
  const i32x4 vz = {0, 0, 0, 0};
#pragma unroll
  for (int m = 0; m < 4; ++m)
#pragma unroll
    for (int n = 0; n < 4; ++n) acc[m][n] = vz;

  // stage k-step ks (BK=64 = 64B/row): 4 x global_load_lds (4KB each)
  auto STAGE = [&](int ks, int buf) __attribute__((always_inline)) {
    const char* aP = aBase + (unsigned)(ks * 64);
    char* ldA = ldsc + buf * 16384 + tid * 16;
#pragma unroll 1
    for (int i2 = 0; i2 < 2; ++i2) {
      __builtin_amdgcn_global_load_lds((const GLOBAL_AS void*)aP,
                                       (LDS_AS void*)ldA, 16, 0, 0);
      aP += 65536; ldA += 4096;  // 64 rows x 1024B global; 64 x 64B LDS
    }
    const char* bP = bBase + (unsigned)(ks * 64);
    char* ldB = ldsc + buf * 16384 + 8192 + tid * 16;
#pragma unroll 1
    for (int i2 = 0; i2 < 2; ++i2) {
      __builtin_amdgcn_global_load_lds((const GLOBAL_AS void*)bP,
                                       (LDS_AS void*)ldB, 16, 0, 0);
      bP += 65536; ldB += 4096;
    }
  };

  STAGE(0, 0);  // prologue: 4 loads in flight
  // K = 1024: 16 steps of BK=64
#pragma unroll 1
  for (int ks = 0; ks < 16; ++ks) {
    const int cur = ks & 1;
    if (ks < 15) {
      STAGE(ks + 1, cur ^ 1);                          // 8 outstanding
      asm volatile("s_waitcnt vmcnt(4)" ::: "memory");  // current landed
    } else {
      asm volatile("s_waitcnt vmcnt(0)" ::: "memory");
    }
    __builtin_amdgcn_s_barrier();  // all waves' current-step loads landed

    const char* bufc = ldsc + cur * 16384;
    i32x4 a[4], b[4];
#pragma unroll
    for (int m = 0; m < 4; ++m) a[m] = *(const i32x4*)(bufc + aoff0 + m * 1024);
#pragma unroll
    for (int n = 0; n < 4; ++n) b[n] = *(const i32x4*)(bufc + boff0 + n * 1024);
#pragma unroll
    for (int m = 0; m < 4; ++m)
#pragma unroll
      for (int n = 0; n < 4; ++n)
        acc[m][n] = __builtin_amdgcn_mfma_i32_16x16x64_i8(a[m], b[n], acc[m][n], 0, 0, 0);
    __builtin_amdgcn_s_barrier();  // reads done before this buf is restaged
  }

  // ---- Epilogue: ws = SUM_j w * sqrt(max(sq_i+sq_j-2g,0)) ----
  const int ibase = ib * 128 + wr * 64 + kg * 4;
  const int jbase = jb * 128 + wc * 64 + r0;
  float sqj[4];
  int idxj[4];
#pragma unroll
  for (int n = 0; n < 4; ++n) {
    sqj[n] = sq[jbase + n * 16];
    idxj[n] = idx[jbase + n * 16];
  }
  const int dslot = jb * 2 + wc;
  float cws[4] = {0.f, 0.f, 0.f, 0.f};  // column (transposed) accumulators
#pragma unroll
  for (int m = 0; m < 4; ++m) {
#pragma unroll
    for (int q = 0; q < 4; ++q) {
      const int i = ibase + m * 16 + q;
      const float sqi = sq[i];
      const int idxi = idx[i];
      float ws = 0.f;
#pragma unroll
      for (int n = 0; n < 4; ++n) {
        const int j = jbase + n * 16;
        const float g = (float)acc[m][n][q] * INV_S2;
        const float d2 = sqi + sqj[n] - 2.f * g;
        const float dd = FSQRT(fmaxf(d2, 0.f));
        const int di = idxi - idxj[n];
        const unsigned diff = (unsigned)(di < 0 ? -di : di);
        // w via 243-entry LDS table (r19-measured faster than branchless)
        const unsigned qd = __umulhi(diff, 17674763u);
        const unsigned rm = diff - qd * 243u;
        float w = w243f[rm];
        if (__builtin_expect(rm == 0u, 0)) {
          int vvv;
          if (diff == 0u) {
            vvv = 11;
          } else {  // v = 5 + v3(qd), qd in 1..242
            unsigned q2 = qd, t2;
            vvv = 5;
            t2 = q2 * 1749801491u; if (t2 <= 159072862u)  { q2 = t2; vvv += 3; }
            t2 = q2 * 2863311531u; if (t2 <= 1431655765u) { q2 = t2; vvv += 1; }
            t2 = q2 * 2863311531u; if (t2 <= 1431655765u) { vvv += 1; }
          }
          w = lut12f[vvv];
        }
        const float wdd = (i == j) ? 0.f : w * dd;
        ws += wdd;
        cws[n] += wdd;
      }
      // row reduce across the 16 lanes holding this C-row (lane bits 0..3)
#pragma unroll
      for (int o = 1; o < 16; o <<= 1) ws += __shfl_xor(ws, o, 64);
      if (r0 == 0) Pws[(size_t)dslot * N + i] = ws;
    }
  }
  // transposed (column) partials -> rows of block jb, slot 2*ib+wr
  if (ib != jb) {
    const int tslot = ib * 2 + wr;
#pragma unroll
    for (int nn = 0; nn < 4; ++nn) {
      float a = cws[nn];
#pragma unroll
      for (int o = 16; o < 64; o <<= 1) a += __shfl_xor(a, o, 64);
      if (kg == 0) Pws[(size_t)tslot * N + jbase + nn * 16] = a;
    }
  }
}

// Per-row: Z_i/PL_i from 3-adic histograms (exact: v3>=k <=> equal mod 3^k),
// then T_i = (PL_i + 2*SUM ws)/Z_i - log Z_i.
__global__ __launch_bounds__(256) void r1_kernel(
    const float* __restrict__ Pws, const int* __restrict__ hist,
    const int* __restrict__ idx, float* __restrict__ t) {
  const int row = blockIdx.x * 256 + threadIdx.x;
  float ws = 0.f;
  for (int s = 0; s < 128; ++s) ws += Pws[(size_t)s * N + row];
  const unsigned mi = (unsigned)idx[row];
  int H[11];
  H[0] = N;
  H[1] = hist[HOFF1 + (mi % 3u)];
  H[2] = hist[HOFF2 + (mi % 9u)];
  H[3] = hist[HOFF3 + (mi % 27u)];
  H[4] = hist[HOFF4 + (mi % 81u)];
  H[5] = hist[HOFF5 + (mi % 243u)];
  H[6] = hist[HOFF6 + (mi % 729u)];
  H[7] = hist[HOFF7 + (mi % 2187u)];
  H[8] = hist[HOFF8 + (mi % 6561u)];
  H[9] = hist[HOFF9 + (mi % 19683u)];
  H[10] = hist[HOFF10 + mi];
  float Z = 0.f, PL = 0.f;
#pragma unroll
  for (int k = 0; k < 10; ++k) {
    const float pl = -2.f * exp2f(-1.5849625007211562f * (float)k);
    const float w = exp2f(1.4426950408889634f * pl);
    const float cnt = (float)(H[k] - H[k + 1]);
    Z = fmaf(cnt, w, Z);
    PL = fmaf(cnt, w * pl, PL);
  }
  Z += (float)H[10];  // diff==0 class: w=1, Pl=0
  t[row] = (PL + 2.f * ws) / Z - logf(Z);
}

// Final deterministic scalar reduction.
__global__ __launch_bounds__(256) void r2_kernel(const float* __restrict__ t,
                                                 float* __restrict__ out) {
  __shared__ float red[256];
  float s = 0.f;
  for (int r = threadIdx.x; r < N; r += 256) s += t[r];
  red[threadIdx.x] = s;
  __syncthreads();
  for (int o = 128; o > 0; o >>= 1) {
    if (threadIdx.x < (unsigned)o) red[threadIdx.x] += red[threadIdx.x + o];
    __syncthreads();
  }
  if (threadIdx.x == 0) out[0] = red[0] / (float)N;
}

extern "C" void kernel_launch(void* const* d_in, const int* in_sizes, int n_in,
                              void* d_out, int out_size, void* d_ws, size_t ws_size,
                              hipStream_t stream) {
  const float* z = (const float*)d_in[0];
  const int* idx = (const int*)d_in[1];
  float* out = (float*)d_out;
  char* ws = (char*)d_ws;
  // workspace layout (~13 MB used)
  signed char* zq = (signed char*)ws;                                  // 8 MB
  float* sq = (float*)(ws + ((size_t)32 << 20));                       // 32 KB
  float* Pws = (float*)(ws + ((size_t)32 << 20) + ((size_t)64 << 10)); // 4 MB
  int* hist = (int*)(Pws + (size_t)128 * N);                           // 354 KB
  float* tt = (float*)(hist + HTOT);                                   // 32 KB

  prep_kernel<<<N, 256, 0, stream>>>(z, zq, sq, hist);
  hist_kernel<<<32, 256, 0, stream>>>(idx, hist);
  fold_kernel<<<78, 256, 0, stream>>>(hist);
  gram_kernel<<<64 * 65 / 2, 256, 0, stream>>>(zq, sq, idx, Pws);
  r1_kernel<<<32, 256, 0, stream>>>(Pws, hist, idx, tt);
  r2_kernel<<<1, 256, 0, stream>>>(tt, out);
}

// Round 24
// 100.828 us; speedup vs baseline: 1.3182x; 1.0479x over previous
//
#include <hip/hip_runtime.h>
#include <hip/hip_bf16.h>
#include <math.h>

#define GLOBAL_AS __attribute__((address_space(1)))
#define LDS_AS __attribute__((address_space(3)))

typedef int i32x4 __attribute__((ext_vector_type(4)));

#define N 8192
#define D 1024
#define QSCALE 18.0f
#define INV_S2 (1.0f / (QSCALE * QSCALE))
// 3-adic histogram layout: H_k (size 3^k) at OFF_k = (3^k-3)/2, k=1..10.
#define HOFF1 0
#define HOFF2 3
#define HOFF3 12
#define HOFF4 39
#define HOFF5 120
#define HOFF6 363
#define HOFF7 1092
#define HOFF8 3279
#define HOFF9 9840
#define HOFF10 29523
#define HTOT 88572

#if __has_builtin(__builtin_amdgcn_sqrtf)
#define FSQRT(x) __builtin_amdgcn_sqrtf(x)  // raw v_sqrt_f32, ~1ulp
#else
#define FSQRT(x) sqrtf(x)
#endif

// Convert z (fp32) -> int8 (q = clamp(rint(x*18), +-127)), exact fp32 row
// sums of squares, and (piggybacked) zero the histogram buffer.
__global__ __launch_bounds__(256) void prep_kernel(
    const float* __restrict__ z, signed char* __restrict__ zq,
    float* __restrict__ sq, int* __restrict__ hist) {
  const int r = blockIdx.x, t = threadIdx.x;
  if (r < 346) {  // zero 88572 ints for hist_kernel (runs after, stream order)
    const int o = r * 256 + t;
    if (o < HTOT) hist[o] = 0;
  }
  const float4 v = *(const float4*)(z + (size_t)r * D + t * 4);
  float f[4] = {v.x, v.y, v.z, v.w};
  int qq[4];
  float s = 0.f;
#pragma unroll
  for (int u = 0; u < 4; ++u) {
    float x = f[u];
    s = fmaf(x, x, s);
    int q = (int)rintf(x * QSCALE);
    q = max(-127, min(127, q));
    qq[u] = q;
  }
  const unsigned packed = (unsigned)(qq[0] & 255) | ((unsigned)(qq[1] & 255) << 8) |
                          ((unsigned)(qq[2] & 255) << 16) | ((unsigned)(qq[3] & 255) << 24);
  *(unsigned*)(zq + (size_t)r * D + t * 4) = packed;
  // deterministic block reduction
#pragma unroll
  for (int o = 32; o >= 1; o >>= 1) s += __shfl_down(s, o, 64);
  __shared__ float red[4];
  const int lane = t & 63, wv = t >> 6;
  if (lane == 0) red[wv] = s;
  __syncthreads();
  if (t == 0) sq[r] = ((red[0] + red[1]) + red[2]) + red[3];
}

// Histogram build: atomics into H_8 and H_10 only (spread counters, low
// contention; integer atomics = deterministic). idx < 3^10.
__global__ __launch_bounds__(256) void hist_kernel(
    const int* __restrict__ idx, int* __restrict__ hist) {
  const unsigned mi = (unsigned)idx[blockIdx.x * 256 + threadIdx.x];
  atomicAdd(&hist[HOFF8 + (mi % 6561u)], 1);
  atomicAdd(&hist[HOFF10 + mi], 1);
}

// Fold: blocks 0..76 derive H_9 from H_10; block 77 derives H_7..H_1 from
// H_8 in LDS (3279 ints, sequential levels with barriers).
__global__ __launch_bounds__(256) void fold_kernel(int* __restrict__ hist) {
  const int b = blockIdx.x, t = threadIdx.x;
  if (b < 77) {
    const int r = b * 256 + t;
    if (r < 19683)
      hist[HOFF9 + r] =
          hist[HOFF10 + r] + hist[HOFF10 + r + 19683] + hist[HOFF10 + r + 39366];
    return;
  }
  // b == 77: levels 7..1. LDS: l7@0(2187) l6@2187(729) l5@2916(243)
  // l4@3159(81) l3@3240(27) l2@3267(9) l1@3276(3).
  __shared__ int lh[3279];
  for (int r = t; r < 2187; r += 256)
    lh[r] = hist[HOFF8 + r] + hist[HOFF8 + r + 2187] + hist[HOFF8 + r + 4374];
  __syncthreads();
  for (int r = t; r < 729; r += 256) lh[2187 + r] = lh[r] + lh[r + 729] + lh[r + 1458];
  __syncthreads();
  for (int r = t; r < 243; r += 256)
    lh[2916 + r] = lh[2187 + r] + lh[2187 + r + 243] + lh[2187 + r + 486];
  __syncthreads();
  for (int r = t; r < 81; r += 256)
    lh[3159 + r] = lh[2916 + r] + lh[2916 + r + 81] + lh[2916 + r + 162];
  __syncthreads();
  for (int r = t; r < 27; r += 256)
    lh[3240 + r] = lh[3159 + r] + lh[3159 + r + 27] + lh[3159 + r + 54];
  __syncthreads();
  if (t < 9) lh[3267 + t] = lh[3240 + t] + lh[3240 + t + 9] + lh[3240 + t + 18];
  __syncthreads();
  if (t < 3) lh[3276 + t] = lh[3267 + t] + lh[3267 + t + 3] + lh[3267 + t + 6];
  __syncthreads();
  for (int r = t; r < 2187; r += 256) hist[HOFF7 + r] = lh[r];
  for (int r = t; r < 729; r += 256) hist[HOFF6 + r] = lh[2187 + r];
  for (int r = t; r < 243; r += 256) hist[HOFF5 + r] = lh[2916 + r];
  if (t < 81) hist[HOFF4 + t] = lh[3159 + t];
  if (t < 27) hist[HOFF3 + t] = lh[3240 + t];
  if (t < 9) hist[HOFF2 + t] = lh[3267 + t];
  if (t < 3) hist[HOFF1 + t] = lh[3276 + t];
}

// Lower-triangle 128x128 tile gram over K=1024 int8, BK=128 SINGLE-buffer,
// launch_bounds(256,3) -- r21's measured-best structure (69.6us) with two
// additive, individually-cheap changes:
//  (a) T5: s_setprio(1) around the MFMA cluster. Prereq (wave role
//      diversity) holds here via 3 INDEPENDENT resident blocks/CU --
//      the regime where setprio measured +4-7% (attn), not the lockstep
//      4-wave null (m190).
//  (b) Epilogue operand prefetch: sqi[16]/idxi[16]/sqj[4]/idxj[4] loaded
//      into registers BEFORE the k-loop (hides ~600cy scattered-load
//      latency under it). Unified regs ~168 <= 170 cap; acid test =
//      WRITE_SIZE stays ~4.1MB.
// dbuf/counted-vmcnt is settled dead: 3 losses (r7, r20, r23-iso).
__global__ __launch_bounds__(256, 3) void gram_kernel(
    const signed char* __restrict__ zq,
    const float* __restrict__ sq, const int* __restrict__ idx,
    float* __restrict__ Pws) {
  __shared__ __align__(16) signed char lds[2 * 128 * 128];  // A, B (32 KiB)
  __shared__ float w243f[244];  // w by diff%243
  __shared__ float lut12f[12];  // w by v3 value; [11] = diff==0
  // triangle decode: blockIdx.x = ib*(ib+1)/2 + jb, jb <= ib
  const int t = blockIdx.x;
  int ibv = (int)((sqrtf(8.f * (float)t + 1.f) - 1.f) * 0.5f);
  while ((ibv + 1) * (ibv + 2) / 2 <= t) ++ibv;
  while (ibv * (ibv + 1) / 2 > t) --ibv;
  const int ib = __builtin_amdgcn_readfirstlane(ibv);
  const int jb = __builtin_amdgcn_readfirstlane(t - ibv * (ibv + 1) / 2);

  const int tid = threadIdx.x;
  const int lane = tid & 63, wv = tid >> 6;
  const int wr = wv >> 1, wc = wv & 1;
  const int r0 = lane & 15, kg = lane >> 4;

  if (tid < 12) {
    const float Pl = (tid == 11) ? 0.f : -2.f * exp2f(-1.5849625007211562f * (float)tid);
    lut12f[tid] = exp2f(1.4426950408889634f * Pl);
  }
  if (tid < 243) {
    int rr = tid, v = 0;
    if (rr > 0) {
      while (rr % 3 == 0) { rr /= 3; ++v; }
    }
    w243f[tid] = exp2f(1.4426950408889634f * (-2.f * exp2f(-1.5849625007211562f * (float)v)));
  }

  // --- epilogue operand prefetch (registers, before the k-loop) ---
  const int ibase = ib * 128 + wr * 64 + kg * 4;
  const int jbase = jb * 128 + wc * 64 + r0;
  float sqj[4];
  int idxj[4];
#pragma unroll
  for (int n = 0; n < 4; ++n) {
    sqj[n] = sq[jbase + n * 16];
    idxj[n] = idx[jbase + n * 16];
  }
  float sqi[16];
  int idxi[16];
#pragma unroll
  for (int m = 0; m < 4; ++m)
#pragma unroll
    for (int q = 0; q < 4; ++q) {
      sqi[m * 4 + q] = sq[ibase + m * 16 + q];
      idxi[m * 4 + q] = idx[ibase + m * 16 + q];
    }

  // --- staging addressing (4-bit-row swizzle over 8 units) ---
  const unsigned vbase =
      ((unsigned)(tid >> 3) * 1024u) + ((unsigned)((tid & 7) ^ ((tid >> 3) & 7)) * 16u);
  const char* aBase = (const char*)(zq + (size_t)ib * 128 * D) + vbase;
  const char* bBase = (const char*)(zq + (size_t)jb * 128 * D) + vbase;
  char* ldsc = (char*)&lds[0];

  // --- LDS read addressing (kc=1 = base ^ 64) ---
  const int ub = kg ^ (r0 & 3);
  const int kcx = (r0 >> 2) & 1;
  const unsigned aoff0 = (unsigned)((wr * 64 + r0) * 128 + (kcx * 4 + ub) * 16);
  const unsigned boff0 = (unsigned)(16384 + (wc * 64 + r0) * 128 + (kcx * 4 + ub) * 16);

  i32x4 acc[4][4];
  const i32x4 vz = {0, 0, 0, 0};
#pragma unroll
  for (int m = 0; m < 4; ++m)
#pragma unroll
    for (int n = 0; n < 4; ++n) acc[m][n] = vz;

  // K = 1024: 8 steps of BK=128 (128B per row-step)
#pragma unroll 1
  for (int ks = 0; ks < 8; ++ks) {
    const char* aP = aBase + (unsigned)(ks * 128);
    const char* bP = bBase + (unsigned)(ks * 128);
    char* ldA = ldsc + tid * 16;
    char* ldB = ldsc + 16384 + tid * 16;
    __syncthreads();
#pragma unroll 1
    for (int i4 = 0; i4 < 4; ++i4) {
      __builtin_amdgcn_global_load_lds((const GLOBAL_AS void*)aP,
                                       (LDS_AS void*)ldA, 16, 0, 0);
      aP += 32768; ldA += 4096;
    }
#pragma unroll 1
    for (int i4 = 0; i4 < 4; ++i4) {
      __builtin_amdgcn_global_load_lds((const GLOBAL_AS void*)bP,
                                       (LDS_AS void*)ldB, 16, 0, 0);
      bP += 32768; ldB += 4096;
    }
    __syncthreads();

#pragma unroll
    for (int kc = 0; kc < 2; ++kc) {
      const unsigned ax = aoff0 ^ (unsigned)(kc * 64);
      const unsigned bx = boff0 ^ (unsigned)(kc * 64);
      i32x4 a[4], b[4];
#pragma unroll
      for (int m = 0; m < 4; ++m) a[m] = *(const i32x4*)(ldsc + ax + m * 2048);
#pragma unroll
      for (int n = 0; n < 4; ++n) b[n] = *(const i32x4*)(ldsc + bx + n * 2048);
      __builtin_amdgcn_s_setprio(1);
#pragma unroll
      for (int m = 0; m < 4; ++m)
#pragma unroll
        for (int n = 0; n < 4; ++n)
          acc[m][n] = __builtin_amdgcn_mfma_i32_16x16x64_i8(a[m], b[n], acc[m][n], 0, 0, 0);
      __builtin_amdgcn_s_setprio(0);
    }
  }

  // ---- Epilogue: ws = SUM_j w * sqrt(max(sq_i+sq_j-2g,0)) ----
  const int dslot = jb * 2 + wc;
  float cws[4] = {0.f, 0.f, 0.f, 0.f};  // column (transposed) accumulators
#pragma unroll
  for (int m = 0; m < 4; ++m) {
#pragma unroll
    for (int q = 0; q < 4; ++q) {
      const int i = ibase + m * 16 + q;
      const float si = sqi[m * 4 + q];
      const int ii = idxi[m * 4 + q];
      float ws = 0.f;
#pragma unroll
      for (int n = 0; n < 4; ++n) {
        const int j = jbase + n * 16;
        const float g = (float)acc[m][n][q] * INV_S2;
        const float d2 = si + sqj[n] - 2.f * g;
        const float dd = FSQRT(fmaxf(d2, 0.f));
        const int di = ii - idxj[n];
        const unsigned diff = (unsigned)(di < 0 ? -di : di);
        // w via 243-entry LDS table (r19-measured faster than branchless)
        const unsigned qd = __umulhi(diff, 17674763u);
        const unsigned rm = diff - qd * 243u;
        float w = w243f[rm];
        if (__builtin_expect(rm == 0u, 0)) {
          int vvv;
          if (diff == 0u) {
            vvv = 11;
          } else {  // v = 5 + v3(qd), qd in 1..242
            unsigned q2 = qd, t2;
            vvv = 5;
            t2 = q2 * 1749801491u; if (t2 <= 159072862u)  { q2 = t2; vvv += 3; }
            t2 = q2 * 2863311531u; if (t2 <= 1431655765u) { q2 = t2; vvv += 1; }
            t2 = q2 * 2863311531u; if (t2 <= 1431655765u) { vvv += 1; }
          }
          w = lut12f[vvv];
        }
        const float wdd = (i == j) ? 0.f : w * dd;
        ws += wdd;
        cws[n] += wdd;
      }
      // row reduce across the 16 lanes holding this C-row (lane bits 0..3)
#pragma unroll
      for (int o = 1; o < 16; o <<= 1) ws += __shfl_xor(ws, o, 64);
      if (r0 == 0) Pws[(size_t)dslot * N + i] = ws;
    }
  }
  // transposed (column) partials -> rows of block jb, slot 2*ib+wr
  if (ib != jb) {
    const int tslot = ib * 2 + wr;
#pragma unroll
    for (int nn = 0; nn < 4; ++nn) {
      float a = cws[nn];
#pragma unroll
      for (int o = 16; o < 64; o <<= 1) a += __shfl_xor(a, o, 64);
      if (kg == 0) Pws[(size_t)tslot * N + jbase + nn * 16] = a;
    }
  }
}

// Per-row: Z_i/PL_i from 3-adic histograms (exact: v3>=k <=> equal mod 3^k),
// then T_i = (PL_i + 2*SUM ws)/Z_i - log Z_i.
__global__ __launch_bounds__(256) void r1_kernel(
    const float* __restrict__ Pws, const int* __restrict__ hist,
    const int* __restrict__ idx, float* __restrict__ t) {
  const int row = blockIdx.x * 256 + threadIdx.x;
  float ws = 0.f;
  for (int s = 0; s < 128; ++s) ws += Pws[(size_t)s * N + row];
  const unsigned mi = (unsigned)idx[row];
  int H[11];
  H[0] = N;
  H[1] = hist[HOFF1 + (mi % 3u)];
  H[2] = hist[HOFF2 + (mi % 9u)];
  H[3] = hist[HOFF3 + (mi % 27u)];
  H[4] = hist[HOFF4 + (mi % 81u)];
  H[5] = hist[HOFF5 + (mi % 243u)];
  H[6] = hist[HOFF6 + (mi % 729u)];
  H[7] = hist[HOFF7 + (mi % 2187u)];
  H[8] = hist[HOFF8 + (mi % 6561u)];
  H[9] = hist[HOFF9 + (mi % 19683u)];
  H[10] = hist[HOFF10 + mi];
  float Z = 0.f, PL = 0.f;
#pragma unroll
  for (int k = 0; k < 10; ++k) {
    const float pl = -2.f * exp2f(-1.5849625007211562f * (float)k);
    const float w = exp2f(1.4426950408889634f * pl);
    const float cnt = (float)(H[k] - H[k + 1]);
    Z = fmaf(cnt, w, Z);
    PL = fmaf(cnt, w * pl, PL);
  }
  Z += (float)H[10];  // diff==0 class: w=1, Pl=0
  t[row] = (PL + 2.f * ws) / Z - logf(Z);
}

// Final deterministic scalar reduction.
__global__ __launch_bounds__(256) void r2_kernel(const float* __restrict__ t,
                                                 float* __restrict__ out) {
  __shared__ float red[256];
  float s = 0.f;
  for (int r = threadIdx.x; r < N; r += 256) s += t[r];
  red[threadIdx.x] = s;
  __syncthreads();
  for (int o = 128; o > 0; o >>= 1) {
    if (threadIdx.x < (unsigned)o) red[threadIdx.x] += red[threadIdx.x + o];
    __syncthreads();
  }
  if (threadIdx.x == 0) out[0] = red[0] / (float)N;
}

extern "C" void kernel_launch(void* const* d_in, const int* in_sizes, int n_in,
                              void* d_out, int out_size, void* d_ws, size_t ws_size,
                              hipStream_t stream) {
  const float* z = (const float*)d_in[0];
  const int* idx = (const int*)d_in[1];
  float* out = (float*)d_out;
  char* ws = (char*)d_ws;
  // workspace layout (~13 MB used)
  signed char* zq = (signed char*)ws;                                  // 8 MB
  float* sq = (float*)(ws + ((size_t)32 << 20));                       // 32 KB
  float* Pws = (float*)(ws + ((size_t)32 << 20) + ((size_t)64 << 10)); // 4 MB
  int* hist = (int*)(Pws + (size_t)128 * N);                           // 354 KB
  float* tt = (float*)(hist + HTOT);                                   // 32 KB

  prep_kernel<<<N, 256, 0, stream>>>(z, zq, sq, hist);
  hist_kernel<<<32, 256, 0, stream>>>(idx, hist);
  fold_kernel<<<78, 256, 0, stream>>>(hist);
  gram_kernel<<<64 * 65 / 2, 256, 0, stream>>>(zq, sq, idx, Pws);
  r1_kernel<<<32, 256, 0, stream>>>(Pws, hist, idx, tt);
  r2_kernel<<<1, 256, 0, stream>>>(tt, out);
}